// Round 4
// baseline (213.116 us; speedup 1.0000x reference)
//
#include <hip/hip_runtime.h>
#include <hip/hip_bf16.h>

// B=4, S=2048, E=512, H=8, D=64, F=2048
// Attention via exact Gaussian-kernel Taylor factorization (R=16 terms), with the
// V projection folded AFTER the k-sum:  M[n,:] = (sum_k w_n(k) xh[k,:]) @ Wv[h] + den_n*bv.
// MLP via bf16 MFMA (16x16x32), 128x128 tile, BK=32, global_load_lds w16,
// 2-phase double-buffered LDS pipeline (T3 minimal: stage next || compute cur).

#define Bsz 4
#define Ssz 2048
#define Esz 512
#define Hsz 8
#define Dsz 64
#define Fsz 2048
#define NR 16      // Taylor terms
#define NCH 16     // k-chunks
#define CHK 128    // k per chunk

typedef __attribute__((ext_vector_type(8))) short bf16x8;
typedef __attribute__((ext_vector_type(4))) float f32x4;

// 1/sqrt(n), n=1..15 (RS[0] unused)
__device__ __constant__ float RS[16] = {
    0.f, 1.0f, 0.70710678f, 0.57735027f, 0.5f, 0.44721360f, 0.40824829f,
    0.37796447f, 0.35355339f, 0.33333333f, 0.31622777f, 0.30151134f,
    0.28867513f, 0.27735010f, 0.26726124f, 0.25819889f};

static __device__ __forceinline__ void gload_lds16(const void* g, void* l) {
    __builtin_amdgcn_global_load_lds(
        (const __attribute__((address_space(1))) unsigned int*)g,
        (__attribute__((address_space(3))) unsigned int*)l, 16, 0, 0);
}

static __device__ __forceinline__ unsigned short f2bf(float f) {
    unsigned int b = __float_as_uint(f);
    b += 0x7FFFu + ((b >> 16) & 1u);
    return (unsigned short)(b >> 16);
}

// ---------------- K1: LayerNorm (wave per token) + Q/K scalars + xnorm bf16 ----------------
// Xn layout: [bh][s][d]  (per-head rows, d contiguous)
__global__ __launch_bounds__(256) void ln_qk_kernel(
    const float* __restrict__ x,
    const float* __restrict__ Wq, const float* __restrict__ bq,
    const float* __restrict__ Wk, const float* __restrict__ bk,
    float* __restrict__ Qo, float* __restrict__ Ko, __hip_bfloat16* __restrict__ Xn)
{
    int wid = threadIdx.x >> 6, lane = threadIdx.x & 63;
    int tok = blockIdx.x * 4 + wid;
    int b = tok >> 11, s = tok & 2047;

    const float* xrow = x + (size_t)tok * Esz;
    float4 v0 = *(const float4*)&xrow[lane * 8];
    float4 v1 = *(const float4*)&xrow[lane * 8 + 4];

    float sum = v0.x + v0.y + v0.z + v0.w + v1.x + v1.y + v1.z + v1.w;
    #pragma unroll
    for (int off = 32; off > 0; off >>= 1) sum += __shfl_xor(sum, off);
    float mean = sum * (1.0f / 512.0f);

    float d[8] = {v0.x - mean, v0.y - mean, v0.z - mean, v0.w - mean,
                  v1.x - mean, v1.y - mean, v1.z - mean, v1.w - mean};
    float ss = 0.f;
    #pragma unroll
    for (int j = 0; j < 8; ++j) ss = fmaf(d[j], d[j], ss);
    #pragma unroll
    for (int off = 32; off > 0; off >>= 1) ss += __shfl_xor(ss, off);
    float inv = rsqrtf(ss * (1.0f / 512.0f) + 1e-5f);

    float xn[8];
    #pragma unroll
    for (int j = 0; j < 8; ++j) xn[j] = d[j] * inv;

    int h = lane >> 3, dsub = (lane & 7) * 8;
    union { bf16x8 v; unsigned short u[8]; } pk;
    #pragma unroll
    for (int j = 0; j < 8; ++j) pk.u[j] = f2bf(xn[j]);
    *(bf16x8*)((unsigned short*)Xn + (((size_t)(b * Hsz + h) * Ssz + s) * Dsz + dsub)) = pk.v;

    float4 wqa = *(const float4*)&Wq[h * 64 + dsub];
    float4 wqb = *(const float4*)&Wq[h * 64 + dsub + 4];
    float4 wka = *(const float4*)&Wk[h * 64 + dsub];
    float4 wkb = *(const float4*)&Wk[h * 64 + dsub + 4];
    float pq = xn[0]*wqa.x + xn[1]*wqa.y + xn[2]*wqa.z + xn[3]*wqa.w
             + xn[4]*wqb.x + xn[5]*wqb.y + xn[6]*wqb.z + xn[7]*wqb.w;
    float pkv = xn[0]*wka.x + xn[1]*wka.y + xn[2]*wka.z + xn[3]*wka.w
              + xn[4]*wkb.x + xn[5]*wkb.y + xn[6]*wkb.z + xn[7]*wkb.w;
    #pragma unroll
    for (int off = 1; off < 8; off <<= 1) {
        pq  += __shfl_xor(pq, off);
        pkv += __shfl_xor(pkv, off);
    }
    if ((lane & 7) == 0) {
        int bh = b * Hsz + h;
        Qo[bh * Ssz + s] = pq + bq[h];
        Ko[bh * Ssz + s] = pkv + bk[h];
    }
}

// ---------------- K2a: G partials:  Gp[bh][chunk][n][68] = sum_k w_n(k) xh[k,:] (+den at col64) ----------------
__global__ __launch_bounds__(256) void attn_moments(
    const float* __restrict__ Kv, const __hip_bfloat16* __restrict__ Xn, float* __restrict__ Gp)
{
    int chunk = blockIdx.x, bh = blockIdx.y;
    int t = threadIdx.x;
    __shared__ float Wt[CHK][17];
    __shared__ float denp[4][16];

    if (t < CHK) {
        float kv = Kv[bh * Ssz + chunk * CHK + t];
        float wn = __expf(-0.125f * kv * kv);
        float half = 0.5f * kv;
        Wt[t][0] = wn;
        #pragma unroll
        for (int n = 1; n < NR; ++n) { wn *= half * RS[n]; Wt[t][n] = wn; }
    }
    __syncthreads();

    int w = t >> 6, lane = t & 63;
    int ng = w * 4;
    float a0 = 0.f, a1 = 0.f, a2 = 0.f, a3 = 0.f;
    const __hip_bfloat16* xb = Xn + ((size_t)bh * Ssz + chunk * CHK) * Dsz + lane;
    for (int k = 0; k < CHK; ++k) {
        float v = __bfloat162float(xb[(size_t)k * Dsz]);
        a0 = fmaf(Wt[k][ng + 0], v, a0);
        a1 = fmaf(Wt[k][ng + 1], v, a1);
        a2 = fmaf(Wt[k][ng + 2], v, a2);
        a3 = fmaf(Wt[k][ng + 3], v, a3);
    }
    size_t base = (((size_t)bh * NCH + chunk) * NR + ng) * 68 + lane;
    Gp[base + 0 * 68] = a0;
    Gp[base + 1 * 68] = a1;
    Gp[base + 2 * 68] = a2;
    Gp[base + 3 * 68] = a3;

    if (t < 64) {
        int n = t & 15, q = t >> 4;
        float s = 0.f;
        #pragma unroll
        for (int kk = 0; kk < CHK / 4; ++kk) s += Wt[q * (CHK / 4) + kk][n];
        denp[q][n] = s;
    }
    __syncthreads();
    if (t < 16) {
        float m = denp[0][t] + denp[1][t] + denp[2][t] + denp[3][t];
        Gp[(((size_t)bh * NCH + chunk) * NR + t) * 68 + 64] = m;
    }
}

// ---------------- K2b: reduce chunks + apply Wv:  M[n,d] = G[n,:]@Wv[h][:,d] + den_n*bv ----------------
__global__ __launch_bounds__(256) void attn_mtransform(
    const float* __restrict__ Gp, const float* __restrict__ Wv, const float* __restrict__ bv,
    float* __restrict__ M)
{
    int bh = blockIdx.x, h = bh & 7, t = threadIdx.x;
    __shared__ float Gf[NR * 68];
    for (int i = t; i < NR * 68; i += 256) {
        float s = 0.f;
        #pragma unroll
        for (int c = 0; c < NCH; ++c)
            s += Gp[(((size_t)bh * NCH + c) * NR) * 68 + i];
        Gf[i] = s;
    }
    __syncthreads();
    #pragma unroll
    for (int rep = 0; rep < 4; ++rep) {
        int o = t + rep * 256;
        int n = o >> 6, dd = o & 63;
        float den = Gf[n * 68 + 64];
        float acc = den * bv[h * 64 + dd];
        const float* wv = Wv + ((size_t)h * 64) * 64 + dd;
        #pragma unroll
        for (int e = 0; e < 64; ++e) acc = fmaf(Gf[n * 68 + e], wv[(size_t)e * 64], acc);
        M[(size_t)bh * NR * 68 + n * 68 + dd] = acc;
        if (dd == 0) M[(size_t)bh * NR * 68 + n * 68 + 64] = den;
    }
}

// ---------------- K2c: apply Q-side, write head_out as bf16 [8192,512] ----------------
__global__ __launch_bounds__(256) void attn_apply(
    const float* __restrict__ Qv, const float* __restrict__ M, __hip_bfloat16* __restrict__ A1)
{
    int tok = blockIdx.x;
    int b = tok >> 11, s = tok & 2047;
    int t = threadIdx.x;
    #pragma unroll
    for (int rep = 0; rep < 2; ++rep) {
        int e = t + rep * 256;
        int h = e >> 6, dd = e & 63;
        int bh = b * 8 + h;
        float q = Qv[bh * Ssz + s];
        const float* Mb = M + (size_t)bh * NR * 68;
        float half = 0.5f * q;
        float phi = 1.0f;
        float num = Mb[dd], den = Mb[64];
        #pragma unroll
        for (int n = 1; n < NR; ++n) {
            phi *= half * RS[n];
            num = fmaf(phi, Mb[n * 68 + dd], num);
            den = fmaf(phi, Mb[n * 68 + 64], den);
        }
        A1[(size_t)tok * Esz + e] = __float2bfloat16(num / den);
    }
}

// ---------------- transpose + fp32->bf16: out[C][R] = in[R][C] ----------------
__global__ __launch_bounds__(256) void transpose_bf16(
    const float* __restrict__ in, __hip_bfloat16* __restrict__ out, int R, int C)
{
    __shared__ float tile[32][33];
    int bx = blockIdx.x, by = blockIdx.y;
    int t = threadIdx.x;
    int tc = t & 31, tr = t >> 5;
    #pragma unroll
    for (int i = 0; i < 4; ++i) {
        int r = by * 32 + tr + i * 8, c = bx * 32 + tc;
        tile[tr + i * 8][tc] = in[(size_t)r * C + c];
    }
    __syncthreads();
    #pragma unroll
    for (int i = 0; i < 4; ++i) {
        int ro = bx * 32 + tr + i * 8, co = by * 32 + tc;
        out[(size_t)ro * R + co] = __float2bfloat16(tile[tc][tr + i * 8]);
    }
}

// ---------------- bf16 MFMA GEMM: C = A[M,K] * Bt[N,K]^T, 128x128 tile, BK=32 ----------------
// 2-phase double-buffered: stage K-tile t+1 into buf^1 while computing buf[cur].
// EPI=0: out bf16 = gelu(acc + bias). EPI=1: out f32 = acc + bias + resid.
template <int KDIM, int EPI>
__global__ __launch_bounds__(256) void gemm_bf16(
    const __hip_bfloat16* __restrict__ A, const __hip_bfloat16* __restrict__ Bt,
    const float* __restrict__ bias, const float* __restrict__ resid,
    void* __restrict__ Out, int N)
{
    __shared__ unsigned short As[2][128][32];
    __shared__ unsigned short Bs[2][128][32];
    int t = threadIdx.x;
    int w = t >> 6, lane = t & 63;
    int wr = w >> 1, wc = w & 1;
    int bm = blockIdx.y * 128, bn = blockIdx.x * 128;

    f32x4 acc[4][4] = {};
    const int r = t >> 2, cg = (t & 3) * 8;

    // prologue: stage K-tile 0
    {
        gload_lds16(&A[(size_t)(bm + r) * KDIM + cg], &As[0][r][cg]);
        gload_lds16(&A[(size_t)(bm + r + 64) * KDIM + cg], &As[0][r + 64][cg]);
        gload_lds16(&Bt[(size_t)(bn + r) * KDIM + cg], &Bs[0][r][cg]);
        gload_lds16(&Bt[(size_t)(bn + r + 64) * KDIM + cg], &Bs[0][r + 64][cg]);
    }
    __syncthreads();   // drains vmcnt -> buf0 ready

    int cur = 0;
    for (int k0 = 0; k0 < KDIM; k0 += 32) {
        // issue next tile's loads into the other buffer (latency hides under MFMA)
        if (k0 + 32 < KDIM) {
            int nk = k0 + 32, nb = cur ^ 1;
            gload_lds16(&A[(size_t)(bm + r) * KDIM + nk + cg], &As[nb][r][cg]);
            gload_lds16(&A[(size_t)(bm + r + 64) * KDIM + nk + cg], &As[nb][r + 64][cg]);
            gload_lds16(&Bt[(size_t)(bn + r) * KDIM + nk + cg], &Bs[nb][r][cg]);
            gload_lds16(&Bt[(size_t)(bn + r + 64) * KDIM + nk + cg], &Bs[nb][r + 64][cg]);
        }
        bf16x8 af[4], bfr[4];
        #pragma unroll
        for (int i = 0; i < 4; ++i) {
            af[i]  = *(const bf16x8*)&As[cur][wr * 64 + i * 16 + (lane & 15)][(lane >> 4) * 8];
            bfr[i] = *(const bf16x8*)&Bs[cur][wc * 64 + i * 16 + (lane & 15)][(lane >> 4) * 8];
        }
        #pragma unroll
        for (int i = 0; i < 4; ++i)
            #pragma unroll
            for (int j = 0; j < 4; ++j)
                acc[i][j] = __builtin_amdgcn_mfma_f32_16x16x32_bf16(af[i], bfr[j], acc[i][j], 0, 0, 0);
        __syncthreads();   // next buffer staged + everyone done reading cur
        cur ^= 1;
    }

    int col0 = lane & 15, rowg = lane >> 4;
    #pragma unroll
    for (int i = 0; i < 4; ++i) {
        #pragma unroll
        for (int j = 0; j < 4; ++j) {
            #pragma unroll
            for (int v = 0; v < 4; ++v) {
                int m = bm + wr * 64 + i * 16 + rowg * 4 + v;
                int n = bn + wc * 64 + j * 16 + col0;
                float val = acc[i][j][v] + bias[n];
                if (EPI == 0) {
                    float g = 0.5f * val * (1.0f + erff(val * 0.70710678f));
                    ((__hip_bfloat16*)Out)[(size_t)m * N + n] = __float2bfloat16(g);
                } else {
                    size_t idx = (size_t)m * N + n;
                    ((float*)Out)[idx] = val + resid[idx];
                }
            }
        }
    }
}

extern "C" void kernel_launch(void* const* d_in, const int* in_sizes, int n_in,
                              void* d_out, int out_size, void* d_ws, size_t ws_size,
                              hipStream_t stream) {
    const float* x  = (const float*)d_in[0];
    const float* Wv = (const float*)d_in[1];
    const float* bv = (const float*)d_in[2];
    const float* Wq = (const float*)d_in[3];
    const float* bq = (const float*)d_in[4];
    const float* Wk = (const float*)d_in[5];
    const float* bk = (const float*)d_in[6];
    const float* W1 = (const float*)d_in[7];
    const float* b1 = (const float*)d_in[8];
    const float* W2 = (const float*)d_in[9];
    const float* b2 = (const float*)d_in[10];
    float* out = (float*)d_out;

    char* ws = (char*)d_ws;
    float* Qb    = (float*)(ws + 0);                     // 256 KB
    float* Kb    = (float*)(ws + 262144);                // 256 KB
    __hip_bfloat16* Xn = (__hip_bfloat16*)(ws + 524288); // 8 MB  [bh][s][d]
    float* Gp    = (float*)(ws + 8912896);               // 2.23 MB
    float* Mfull = (float*)(ws + 11141120);              // 139 KB
    __hip_bfloat16* A1   = (__hip_bfloat16*)(ws + 11280384); // 8 MB
    __hip_bfloat16* W1T  = (__hip_bfloat16*)(ws + 19668992); // 2 MB
    __hip_bfloat16* W2T  = (__hip_bfloat16*)(ws + 21766144); // 2 MB
    __hip_bfloat16* hbuf = (__hip_bfloat16*)(ws + 23863296); // 32 MB

    ln_qk_kernel<<<dim3((Bsz * Ssz) / 4), 256, 0, stream>>>(x, Wq, bq, Wk, bk, Qb, Kb, Xn);
    attn_moments<<<dim3(NCH, Bsz * Hsz), 256, 0, stream>>>(Kb, Xn, Gp);
    attn_mtransform<<<dim3(Bsz * Hsz), 256, 0, stream>>>(Gp, Wv, bv, Mfull);
    attn_apply<<<dim3(Bsz * Ssz), 256, 0, stream>>>(Qb, Mfull, A1);
    transpose_bf16<<<dim3(Fsz / 32, Esz / 32), 256, 0, stream>>>(W1, W1T, Esz, Fsz);
    transpose_bf16<<<dim3(Esz / 32, Fsz / 32), 256, 0, stream>>>(W2, W2T, Fsz, Esz);
    gemm_bf16<Esz, 0><<<dim3(Fsz / 128, (Bsz * Ssz) / 128), 256, 0, stream>>>(A1, W1T, b1, nullptr, hbuf, Fsz);
    gemm_bf16<Fsz, 1><<<dim3(Esz / 128, (Bsz * Ssz) / 128), 256, 0, stream>>>(hbuf, W2T, b2, x, out, Esz);
}